// Round 1
// baseline (935.094 us; speedup 1.0000x reference)
//
#include <hip/hip_runtime.h>
#include <hip/hip_bf16.h>

#define CH 128
#define CH4 32

constexpr float BN_EPS = 1e-5f;

__device__ __forceinline__ float dot4(float4 a, float4 b) {
    return a.x*b.x + a.y*b.y + a.z*b.z + a.w*b.w;
}

// ---------------------------------------------------------------------------
// Kernel U: u[n] = W1[:, :128] @ x[n],  v[n] = W1[:, 128:] @ x[n]
// block = 256 threads, 32 nodes/block. x tile in LDS (broadcast reads),
// W1 rows streamed from L1/L2.
// ---------------------------------------------------------------------------
__global__ __launch_bounds__(256) void node_linear_kernel(
    const float* __restrict__ x, const float* __restrict__ W1,
    float* __restrict__ u, float* __restrict__ v, int N)
{
    __shared__ float4 xs[32 * 32];   // 32 nodes x 32 float4 (16 KB)
    const int t = threadIdx.x;
    const int n0 = blockIdx.x * 32;
    const float4* x4 = (const float4*)x;
    #pragma unroll
    for (int k = 0; k < 4; ++k) {
        int flat = t + k * 256;
        int row = flat >> 5, c4 = flat & 31;
        int n = n0 + row;
        xs[flat] = (n < N) ? x4[(size_t)n * CH4 + c4] : make_float4(0.f, 0.f, 0.f, 0.f);
    }
    __syncthreads();

    const int o = t & 127;
    const int half = t >> 7;
    const float4* W14 = (const float4*)W1;   // [128][64] float4 (row = 256 floats)
    float accu[16], accv[16];
    #pragma unroll
    for (int n = 0; n < 16; ++n) { accu[n] = 0.f; accv[n] = 0.f; }

    #pragma unroll 4
    for (int c4 = 0; c4 < 32; ++c4) {
        float4 wa = W14[o * 64 + c4];
        float4 wb = W14[o * 64 + 32 + c4];
        #pragma unroll
        for (int n = 0; n < 16; ++n) {
            float4 xv = xs[(half * 16 + n) * 32 + c4];   // LDS broadcast
            accu[n] += dot4(wa, xv);
            accv[n] += dot4(wb, xv);
        }
    }
    #pragma unroll
    for (int n = 0; n < 16; ++n) {
        int node = n0 + half * 16 + n;
        if (node < N) {
            u[(size_t)node * CH + o] = accu[n];
            v[(size_t)node * CH + o] = accv[n];
        }
    }
}

// ---------------------------------------------------------------------------
// Kernel S1: per-edge h1 = u[src]+v[dst]+b1; accumulate per-channel sum/sumsq.
// Half-wave (32 lanes, float4 each) per edge -> 512B coalesced row reads.
// Register accumulate -> LDS reduce -> per-block partials (deterministic).
// ---------------------------------------------------------------------------
__global__ __launch_bounds__(256) void stats1_kernel(
    const float* __restrict__ u, const float* __restrict__ v,
    const int* __restrict__ src, const int* __restrict__ dst,
    const float* __restrict__ b1, float* __restrict__ partials, int E)
{
    const int t = threadIdx.x;
    const int c4 = t & 31;
    const int eslot = t >> 5;
    const float4* u4 = (const float4*)u;
    const float4* v4 = (const float4*)v;
    const float4 bv = ((const float4*)b1)[c4];

    float rs0=0.f, rs1=0.f, rs2=0.f, rs3=0.f;
    float rq0=0.f, rq1=0.f, rq2=0.f, rq3=0.f;

    const int iters = (E + 7) >> 3;
    for (int it = blockIdx.x; it < iters; it += gridDim.x) {
        int e = it * 8 + eslot;
        if (e < E) {
            int s = src[e], d = dst[e];
            float4 a = u4[(size_t)s * CH4 + c4];
            float4 b = v4[(size_t)d * CH4 + c4];
            float h0 = a.x + b.x + bv.x;
            float h1 = a.y + b.y + bv.y;
            float h2 = a.z + b.z + bv.z;
            float h3 = a.w + b.w + bv.w;
            rs0 += h0; rq0 += h0 * h0;
            rs1 += h1; rq1 += h1 * h1;
            rs2 += h2; rq2 += h2 * h2;
            rs3 += h3; rq3 += h3 * h3;
        }
    }
    __shared__ float red[256];
    red[t] = 0.f;
    __syncthreads();
    int c = c4 * 4;
    atomicAdd(&red[c + 0], rs0); atomicAdd(&red[c + 1], rs1);
    atomicAdd(&red[c + 2], rs2); atomicAdd(&red[c + 3], rs3);
    atomicAdd(&red[128 + c + 0], rq0); atomicAdd(&red[128 + c + 1], rq1);
    atomicAdd(&red[128 + c + 2], rq2); atomicAdd(&red[128 + c + 3], rq3);
    __syncthreads();
    partials[(size_t)blockIdx.x * 256 + t] = red[t];
}

// ---------------------------------------------------------------------------
// Finalize: mean/var -> scale = g*rsqrt(var+eps), shift = be - mean*scale
// ---------------------------------------------------------------------------
__global__ __launch_bounds__(128) void finalize_kernel(
    const float* __restrict__ partials, int nblocks,
    const float* __restrict__ gamma, const float* __restrict__ beta,
    float* __restrict__ scale, float* __restrict__ shift, float invE)
{
    const int t = threadIdx.x;   // 0..127
    float s = 0.f, q = 0.f;
    for (int b = 0; b < nblocks; ++b) {
        s += partials[(size_t)b * 256 + t];
        q += partials[(size_t)b * 256 + 128 + t];
    }
    float mean = s * invE;
    float var = fmaxf(q * invE - mean * mean, 0.f);
    float sc = gamma[t] * rsqrtf(var + BN_EPS);
    scale[t] = sc;
    shift[t] = beta[t] - mean * sc;
}

// ---------------------------------------------------------------------------
// Kernel S2: per edge-tile(64): rebuild y = relu(bn1(u[s]+v[d]+b1)) in LDS,
// h2 = y @ W2^T + b2 via 4x4 register tiles (W2 in LDS, stride-33 float4 pad),
// store h2 (bf16), accumulate layer-2 stats.
// ---------------------------------------------------------------------------
__global__ __launch_bounds__(512) void layer2_kernel(
    const float* __restrict__ u, const float* __restrict__ v,
    const int* __restrict__ src, const int* __restrict__ dst,
    const float* __restrict__ b1,
    const float* __restrict__ scale1, const float* __restrict__ shift1,
    const float* __restrict__ W2, const float* __restrict__ b2,
    __hip_bfloat16* __restrict__ h2, float* __restrict__ partials, int E)
{
    __shared__ float4 W2s[128 * 33];   // 67.6 KB, pad -> 4-way max on col reads
    __shared__ float4 ys[64 * 32];     // 32 KB

    const int t = threadIdx.x;
    // stage W2 into LDS (once)
    const float4* W24 = (const float4*)W2;
    #pragma unroll
    for (int k = 0; k < 8; ++k) {
        int flat = t + k * 512;
        int row = flat >> 5, c4 = flat & 31;
        W2s[row * 33 + c4] = W24[flat];
    }

    const int c4y = t & 31;   // y-build column group (fixed per thread)
    const int eg  = t >> 5;   // 0..15
    const int og  = t & 31;   // compute out-group: outs og + 32*j

    const float4* u4 = (const float4*)u;
    const float4* v4 = (const float4*)v;
    const float4 b1v = ((const float4*)b1)[c4y];
    const float4 sc1 = ((const float4*)scale1)[c4y];
    const float4 sh1 = ((const float4*)shift1)[c4y];
    float b2r[4];
    #pragma unroll
    for (int j = 0; j < 4; ++j) b2r[j] = b2[og + 32 * j];

    float rs[4] = {0.f, 0.f, 0.f, 0.f};
    float rq[4] = {0.f, 0.f, 0.f, 0.f};

    const int ntiles = (E + 63) >> 6;
    for (int tile = blockIdx.x; tile < ntiles; tile += gridDim.x) {
        __syncthreads();   // previous tile's ys reads done before overwrite
        #pragma unroll
        for (int i = 0; i < 4; ++i) {
            int e_loc = eg + 16 * i;
            int e = tile * 64 + e_loc;
            float4 y;
            if (e < E) {
                int s = src[e], d = dst[e];
                float4 a = u4[(size_t)s * CH4 + c4y];
                float4 b = v4[(size_t)d * CH4 + c4y];
                y.x = fmaxf((a.x + b.x + b1v.x) * sc1.x + sh1.x, 0.f);
                y.y = fmaxf((a.y + b.y + b1v.y) * sc1.y + sh1.y, 0.f);
                y.z = fmaxf((a.z + b.z + b1v.z) * sc1.z + sh1.z, 0.f);
                y.w = fmaxf((a.w + b.w + b1v.w) * sc1.w + sh1.w, 0.f);
            } else {
                y = make_float4(0.f, 0.f, 0.f, 0.f);
            }
            ys[e_loc * 32 + c4y] = y;
        }
        __syncthreads();

        float acc[4][4];
        #pragma unroll
        for (int i = 0; i < 4; ++i)
            #pragma unroll
            for (int j = 0; j < 4; ++j) acc[i][j] = 0.f;

        #pragma unroll 4
        for (int c4 = 0; c4 < 32; ++c4) {
            float4 ya[4], wb[4];
            #pragma unroll
            for (int i = 0; i < 4; ++i) ya[i] = ys[(4 * eg + i) * 32 + c4];      // half-wave broadcast
            #pragma unroll
            for (int j = 0; j < 4; ++j) wb[j] = W2s[(og + 32 * j) * 33 + c4];    // <=4-way conflict
            #pragma unroll
            for (int i = 0; i < 4; ++i)
                #pragma unroll
                for (int j = 0; j < 4; ++j)
                    acc[i][j] += dot4(ya[i], wb[j]);
        }

        #pragma unroll
        for (int i = 0; i < 4; ++i) {
            int e = tile * 64 + 4 * eg + i;
            if (e < E) {
                #pragma unroll
                for (int j = 0; j < 4; ++j) {
                    float hv = acc[i][j] + b2r[j];
                    rs[j] += hv;
                    rq[j] += hv * hv;
                    h2[(size_t)e * CH + og + 32 * j] = __float2bfloat16(hv);
                }
            }
        }
    }

    // block-level stats reduction -> partials
    __syncthreads();
    float* red = (float*)ys;
    if (t < 256) red[t] = 0.f;
    __syncthreads();
    #pragma unroll
    for (int j = 0; j < 4; ++j) {
        int ch = og + 32 * j;
        atomicAdd(&red[ch], rs[j]);
        atomicAdd(&red[128 + ch], rq[j]);
    }
    __syncthreads();
    if (t < 256) partials[(size_t)blockIdx.x * 256 + t] = red[t];
}

// ---------------------------------------------------------------------------
// Kernel S3: out[e] = dot(relu(bn2(h2[e])), W3) + b3
// ---------------------------------------------------------------------------
__global__ __launch_bounds__(256) void output_kernel(
    const __hip_bfloat16* __restrict__ h2,
    const float* __restrict__ scale2, const float* __restrict__ shift2,
    const float* __restrict__ W3, const float* __restrict__ b3,
    float* __restrict__ out, int E)
{
    const int t = threadIdx.x;
    const int c4 = t & 31;
    const int eslot = t >> 5;
    const float4 sc = ((const float4*)scale2)[c4];
    const float4 sh = ((const float4*)shift2)[c4];
    const float4 w  = ((const float4*)W3)[c4];
    const float bias = b3[0];

    const int iters = (E + 7) >> 3;
    for (int it = blockIdx.x; it < iters; it += gridDim.x) {
        int e = it * 8 + eslot;
        float p = 0.f;
        if (e < E) {
            const uint2 raw = *(const uint2*)((const char*)h2 + ((size_t)e * CH + c4 * 4) * 2);
            float f0 = __uint_as_float(raw.x << 16);
            float f1 = __uint_as_float(raw.x & 0xffff0000u);
            float f2 = __uint_as_float(raw.y << 16);
            float f3 = __uint_as_float(raw.y & 0xffff0000u);
            float y0 = fmaxf(f0 * sc.x + sh.x, 0.f);
            float y1 = fmaxf(f1 * sc.y + sh.y, 0.f);
            float y2 = fmaxf(f2 * sc.z + sh.z, 0.f);
            float y3 = fmaxf(f3 * sc.w + sh.w, 0.f);
            p = y0 * w.x + y1 * w.y + y2 * w.z + y3 * w.w;
        }
        #pragma unroll
        for (int off = 16; off > 0; off >>= 1)
            p += __shfl_xor(p, off, 64);
        if (c4 == 0 && e < E) out[e] = p + bias;
    }
}

// ---------------------------------------------------------------------------
extern "C" void kernel_launch(void* const* d_in, const int* in_sizes, int n_in,
                              void* d_out, int out_size, void* d_ws, size_t ws_size,
                              hipStream_t stream)
{
    const float* x   = (const float*)d_in[0];
    const int*   ei  = (const int*)d_in[1];
    const float* W1  = (const float*)d_in[2];
    const float* b1  = (const float*)d_in[3];
    const float* g1  = (const float*)d_in[4];
    const float* be1 = (const float*)d_in[5];
    const float* W2  = (const float*)d_in[6];
    const float* b2  = (const float*)d_in[7];
    const float* g2  = (const float*)d_in[8];
    const float* be2 = (const float*)d_in[9];
    const float* W3  = (const float*)d_in[10];
    const float* b3  = (const float*)d_in[11];

    const int N = in_sizes[0] / CH;
    const int E = out_size;              // one output per edge
    const int* src = ei;
    const int* dst = ei + E;

    const int S1_BLOCKS = 1024;
    const int S2_BLOCKS = 256;

    // workspace layout (all 16B-aligned)
    float* u = (float*)d_ws;                                  // N*128 f32
    float* v = u + (size_t)N * CH;                            // N*128 f32
    __hip_bfloat16* h2 = (__hip_bfloat16*)(v + (size_t)N * CH);  // E*128 bf16
    float* part1 = (float*)(h2 + (size_t)E * CH);             // S1_BLOCKS*256
    float* part2 = part1 + (size_t)S1_BLOCKS * 256;           // S2_BLOCKS*256
    float* scale1 = part2 + (size_t)S2_BLOCKS * 256;
    float* shift1 = scale1 + CH;
    float* scale2 = shift1 + CH;
    float* shift2 = scale2 + CH;
    float* out = (float*)d_out;

    node_linear_kernel<<<(N + 31) / 32, 256, 0, stream>>>(x, W1, u, v, N);
    stats1_kernel<<<S1_BLOCKS, 256, 0, stream>>>(u, v, src, dst, b1, part1, E);
    finalize_kernel<<<1, 128, 0, stream>>>(part1, S1_BLOCKS, g1, be1, scale1, shift1, 1.0f / (float)E);
    layer2_kernel<<<S2_BLOCKS, 512, 0, stream>>>(u, v, src, dst, b1, scale1, shift1,
                                                 W2, b2, h2, part2, E);
    finalize_kernel<<<1, 128, 0, stream>>>(part2, S2_BLOCKS, g2, be2, scale2, shift2, 1.0f / (float)E);
    output_kernel<<<2048, 256, 0, stream>>>(h2, scale2, shift2, W3, b3, out, E);
}

// Round 2
// 427.053 us; speedup vs baseline: 2.1896x; 2.1896x over previous
//
#include <hip/hip_runtime.h>
#include <hip/hip_bf16.h>

#define CH 128
#define CH4 32

constexpr float BN_EPS = 1e-5f;

typedef short bf16x8 __attribute__((ext_vector_type(8)));
typedef float f32x4  __attribute__((ext_vector_type(4)));

__device__ __forceinline__ unsigned short f2bf(float f) {
    unsigned u = __float_as_uint(f);
    unsigned r = (u + 0x7fffu + ((u >> 16) & 1u)) >> 16;   // RNE
    return (unsigned short)r;
}
__device__ __forceinline__ float bf2f_lo(unsigned u) { return __uint_as_float(u << 16); }
__device__ __forceinline__ float bf2f_hi(unsigned u) { return __uint_as_float(u & 0xffff0000u); }
__device__ __forceinline__ float dot4(float4 a, float4 b) {
    return a.x*b.x + a.y*b.y + a.z*b.z + a.w*b.w;
}

// ---------------------------------------------------------------------------
// Kernel U: u[n] = W1[:, :128] @ x[n],  v[n] = W1[:, 128:] @ x[n]  (bf16 out)
// ---------------------------------------------------------------------------
__global__ __launch_bounds__(256) void node_linear_kernel(
    const float* __restrict__ x, const float* __restrict__ W1,
    unsigned short* __restrict__ u_bf, unsigned short* __restrict__ v_bf, int N)
{
    __shared__ float4 xs[32 * 32];   // 32 nodes x 32 float4 (16 KB)
    const int t = threadIdx.x;
    const int n0 = blockIdx.x * 32;
    const float4* x4 = (const float4*)x;
    #pragma unroll
    for (int k = 0; k < 4; ++k) {
        int flat = t + k * 256;
        int row = flat >> 5, c4 = flat & 31;
        int n = n0 + row;
        xs[flat] = (n < N) ? x4[(size_t)n * CH4 + c4] : make_float4(0.f, 0.f, 0.f, 0.f);
    }
    __syncthreads();

    const int o = t & 127;
    const int half = t >> 7;
    const float4* W14 = (const float4*)W1;   // [128][64] float4
    float accu[16], accv[16];
    #pragma unroll
    for (int n = 0; n < 16; ++n) { accu[n] = 0.f; accv[n] = 0.f; }

    #pragma unroll 4
    for (int c4 = 0; c4 < 32; ++c4) {
        float4 wa = W14[o * 64 + c4];
        float4 wb = W14[o * 64 + 32 + c4];
        #pragma unroll
        for (int n = 0; n < 16; ++n) {
            float4 xv = xs[(half * 16 + n) * 32 + c4];
            accu[n] += dot4(wa, xv);
            accv[n] += dot4(wb, xv);
        }
    }
    #pragma unroll
    for (int n = 0; n < 16; ++n) {
        int node = n0 + half * 16 + n;
        if (node < N) {
            u_bf[(size_t)node * CH + o] = f2bf(accu[n]);
            v_bf[(size_t)node * CH + o] = f2bf(accv[n]);
        }
    }
}

// ---------------------------------------------------------------------------
// Kernel S1: per-edge h1 = u[src]+v[dst]+b1 (bf16 gather); sum/sumsq partials.
// ---------------------------------------------------------------------------
__global__ __launch_bounds__(256) void stats1_kernel(
    const unsigned short* __restrict__ u_bf, const unsigned short* __restrict__ v_bf,
    const int* __restrict__ src, const int* __restrict__ dst,
    const float* __restrict__ b1, float* __restrict__ partials, int E)
{
    const int t = threadIdx.x;
    const int c8 = t & 31;          // uint2 index: channels c8*4 .. c8*4+3
    const int eslot = t >> 5;       // 8 edges per iteration
    const uint2* u2 = (const uint2*)u_bf;
    const uint2* v2 = (const uint2*)v_bf;
    const float4 bv = ((const float4*)b1)[c8];

    float rs0=0.f, rs1=0.f, rs2=0.f, rs3=0.f;
    float rq0=0.f, rq1=0.f, rq2=0.f, rq3=0.f;

    const int iters = (E + 7) >> 3;
    for (int it = blockIdx.x; it < iters; it += gridDim.x) {
        int e = it * 8 + eslot;
        if (e < E) {
            int s = src[e], d = dst[e];
            uint2 a = u2[(size_t)s * 32 + c8];
            uint2 b = v2[(size_t)d * 32 + c8];
            float h0 = bf2f_lo(a.x) + bf2f_lo(b.x) + bv.x;
            float h1 = bf2f_hi(a.x) + bf2f_hi(b.x) + bv.y;
            float h2 = bf2f_lo(a.y) + bf2f_lo(b.y) + bv.z;
            float h3 = bf2f_hi(a.y) + bf2f_hi(b.y) + bv.w;
            rs0 += h0; rq0 += h0 * h0;
            rs1 += h1; rq1 += h1 * h1;
            rs2 += h2; rq2 += h2 * h2;
            rs3 += h3; rq3 += h3 * h3;
        }
    }
    __shared__ float red[256];
    red[t] = 0.f;
    __syncthreads();
    int c = c8 * 4;
    atomicAdd(&red[c + 0], rs0); atomicAdd(&red[c + 1], rs1);
    atomicAdd(&red[c + 2], rs2); atomicAdd(&red[c + 3], rs3);
    atomicAdd(&red[128 + c + 0], rq0); atomicAdd(&red[128 + c + 1], rq1);
    atomicAdd(&red[128 + c + 2], rq2); atomicAdd(&red[128 + c + 3], rq3);
    __syncthreads();
    partials[(size_t)blockIdx.x * 256 + t] = red[t];
}

// ---------------------------------------------------------------------------
// Finalize: mean/var -> scale/shift
// ---------------------------------------------------------------------------
__global__ __launch_bounds__(256) void finalize_kernel(
    const float* __restrict__ partials, int nblocks,
    const float* __restrict__ gamma, const float* __restrict__ beta,
    float* __restrict__ scale, float* __restrict__ shift, float invE)
{
    __shared__ float acc[512];
    const int t = threadIdx.x;
    const int ch = t & 127;
    const int half = t >> 7;
    float s = 0.f, q = 0.f;
    for (int b = half; b < nblocks; b += 2) {
        s += partials[(size_t)b * 256 + ch];
        q += partials[(size_t)b * 256 + 128 + ch];
    }
    acc[t] = s; acc[256 + t] = q;
    __syncthreads();
    if (t < 128) {
        float st = acc[t] + acc[128 + t];
        float qt = acc[256 + t] + acc[384 + t];
        float mean = st * invE;
        float var = fmaxf(qt * invE - mean * mean, 0.f);
        float sc = gamma[t] * rsqrtf(var + BN_EPS);
        scale[t] = sc;
        shift[t] = beta[t] - mean * sc;
    }
}

// ---------------------------------------------------------------------------
// Kernel S2 (MFMA): per 64-edge tile: build y=relu(bn1(u[s]+v[d]+b1)) bf16 in
// swizzled LDS; D[o][e] = W2frag (regs) x y (LDS) via mfma 16x16x32; stats2;
// store h2 in raw fragment order: h2raw[(gblk*8 + o/16)*64 + lane] = 4 bf16.
// 8 waves: wave = (ehalf h = w>>2) x (otile-pair p = w&3, o base p*32).
// ---------------------------------------------------------------------------
__global__ __launch_bounds__(512, 4) void layer2_kernel(
    const unsigned short* __restrict__ u_bf, const unsigned short* __restrict__ v_bf,
    const int* __restrict__ src, const int* __restrict__ dst,
    const float* __restrict__ b1,
    const float* __restrict__ scale1, const float* __restrict__ shift1,
    const float* __restrict__ W2, const float* __restrict__ b2,
    uint2* __restrict__ h2raw, float* __restrict__ partials, int E)
{
    __shared__ short ybuf[64 * 128];   // 16 KB, XOR-swizzled bf16 y tile
    __shared__ float red[256];

    const int t = threadIdx.x;
    const int lane = t & 63;
    const int wv = t >> 6;      // wave 0..7
    const int p = wv & 3;       // otile pair -> o base = p*32
    const int h = wv >> 2;      // e-half (edges h*32 .. h*32+31)
    const int l15 = lane & 15;
    const int l4  = lane >> 4;

    // --- stationary W2 A-fragments (bf16): A[row=o][k], k=(l>>4)*8+j ---
    bf16x8 wfrag[2][4];
    #pragma unroll
    for (int ot = 0; ot < 2; ++ot) {
        int o = p * 32 + ot * 16 + l15;
        #pragma unroll
        for (int kk = 0; kk < 4; ++kk) {
            const float* wp = W2 + (size_t)o * CH + kk * 32 + l4 * 8;
            float4 a = *(const float4*)wp;
            float4 bq = *(const float4*)(wp + 4);
            bf16x8 f;
            f[0]=(short)f2bf(a.x);  f[1]=(short)f2bf(a.y);
            f[2]=(short)f2bf(a.z);  f[3]=(short)f2bf(a.w);
            f[4]=(short)f2bf(bq.x); f[5]=(short)f2bf(bq.y);
            f[6]=(short)f2bf(bq.z); f[7]=(short)f2bf(bq.w);
            wfrag[ot][kk] = f;
        }
    }
    float b2r[2][4];
    #pragma unroll
    for (int ot = 0; ot < 2; ++ot)
        #pragma unroll
        for (int r = 0; r < 4; ++r)
            b2r[ot][r] = b2[p * 32 + ot * 16 + l4 * 4 + r];

    // --- build-phase constants: this thread owns channels cb..cb+7 ---
    const int c16 = t & 15;          // 16B chunk index within a row
    const int cb = c16 * 8;
    const int ebase = t >> 4;        // edges ebase and ebase+32
    float4 sca = *(const float4*)(scale1 + cb);
    float4 scb = *(const float4*)(scale1 + cb + 4);
    float4 b1a = *(const float4*)(b1 + cb);
    float4 b1b = *(const float4*)(b1 + cb + 4);
    float4 sha = *(const float4*)(shift1 + cb);
    float4 shb = *(const float4*)(shift1 + cb + 4);
    float4 bsa, bsb;   // b1*scale + shift folded
    bsa.x = b1a.x*sca.x + sha.x; bsa.y = b1a.y*sca.y + sha.y;
    bsa.z = b1a.z*sca.z + sha.z; bsa.w = b1a.w*sca.w + sha.w;
    bsb.x = b1b.x*scb.x + shb.x; bsb.y = b1b.y*scb.y + shb.y;
    bsb.z = b1b.z*scb.z + shb.z; bsb.w = b1b.w*scb.w + shb.w;

    float rs[2][4] = {{0.f,0.f,0.f,0.f},{0.f,0.f,0.f,0.f}};
    float rq[2][4] = {{0.f,0.f,0.f,0.f},{0.f,0.f,0.f,0.f}};

    const int ntiles = (E + 63) >> 6;
    for (int tile = blockIdx.x; tile < ntiles; tile += gridDim.x) {
        __syncthreads();   // previous tile's ybuf reads complete
        // ---- build y tile (64 edges x 128 ch, bf16, swizzled) ----
        #pragma unroll
        for (int ee = 0; ee < 2; ++ee) {
            const int e_loc = ebase + ee * 32;
            const int e = tile * 64 + e_loc;
            bf16x8 y8 = {0,0,0,0,0,0,0,0};
            if (e < E) {
                int s = src[e], d = dst[e];
                uint4 ua = *(const uint4*)(u_bf + (size_t)s * CH + cb);
                uint4 va = *(const uint4*)(v_bf + (size_t)d * CH + cb);
                float f0 = bf2f_lo(ua.x) + bf2f_lo(va.x);
                float f1 = bf2f_hi(ua.x) + bf2f_hi(va.x);
                float f2 = bf2f_lo(ua.y) + bf2f_lo(va.y);
                float f3 = bf2f_hi(ua.y) + bf2f_hi(va.y);
                float f4 = bf2f_lo(ua.z) + bf2f_lo(va.z);
                float f5 = bf2f_hi(ua.z) + bf2f_hi(va.z);
                float f6 = bf2f_lo(ua.w) + bf2f_lo(va.w);
                float f7 = bf2f_hi(ua.w) + bf2f_hi(va.w);
                y8[0] = (short)f2bf(fmaxf(f0 * sca.x + bsa.x, 0.f));
                y8[1] = (short)f2bf(fmaxf(f1 * sca.y + bsa.y, 0.f));
                y8[2] = (short)f2bf(fmaxf(f2 * sca.z + bsa.z, 0.f));
                y8[3] = (short)f2bf(fmaxf(f3 * sca.w + bsa.w, 0.f));
                y8[4] = (short)f2bf(fmaxf(f4 * scb.x + bsb.x, 0.f));
                y8[5] = (short)f2bf(fmaxf(f5 * scb.y + bsb.y, 0.f));
                y8[6] = (short)f2bf(fmaxf(f6 * scb.z + bsb.z, 0.f));
                y8[7] = (short)f2bf(fmaxf(f7 * scb.w + bsb.w, 0.f));
            }
            const int slot = c16 ^ (e_loc & 7);
            *(bf16x8*)(ybuf + e_loc * 128 + slot * 8) = y8;
        }
        __syncthreads();

        // ---- MFMA + epilogue ----
        #pragma unroll
        for (int g2 = 0; g2 < 2; ++g2) {
            const int g = h * 2 + g2;
            const int erow = g * 16 + l15;
            f32x4 D0 = {0.f, 0.f, 0.f, 0.f};
            f32x4 D1 = {0.f, 0.f, 0.f, 0.f};
            #pragma unroll
            for (int kk = 0; kk < 4; ++kk) {
                const int slot = (kk * 4 + l4) ^ (l15 & 7);
                bf16x8 yf = *(const bf16x8*)(ybuf + erow * 128 + slot * 8);
                D0 = __builtin_amdgcn_mfma_f32_16x16x32_bf16(wfrag[0][kk], yf, D0, 0, 0, 0);
                D1 = __builtin_amdgcn_mfma_f32_16x16x32_bf16(wfrag[1][kk], yf, D1, 0, 0, 0);
            }
            const int gblk = tile * 4 + g;
            const bool ev = ((size_t)gblk * 16 + l15) < (size_t)E;
            {   // ot = 0
                float h0 = D0[0] + b2r[0][0], h1 = D0[1] + b2r[0][1];
                float h2 = D0[2] + b2r[0][2], h3 = D0[3] + b2r[0][3];
                rs[0][0] += ev ? h0 : 0.f; rq[0][0] += ev ? h0*h0 : 0.f;
                rs[0][1] += ev ? h1 : 0.f; rq[0][1] += ev ? h1*h1 : 0.f;
                rs[0][2] += ev ? h2 : 0.f; rq[0][2] += ev ? h2*h2 : 0.f;
                rs[0][3] += ev ? h3 : 0.f; rq[0][3] += ev ? h3*h3 : 0.f;
                unsigned lo = (unsigned)f2bf(h0) | ((unsigned)f2bf(h1) << 16);
                unsigned hi = (unsigned)f2bf(h2) | ((unsigned)f2bf(h3) << 16);
                h2raw[((size_t)gblk * 8 + p * 2 + 0) * 64 + lane] = make_uint2(lo, hi);
            }
            {   // ot = 1
                float h0 = D1[0] + b2r[1][0], h1 = D1[1] + b2r[1][1];
                float h2 = D1[2] + b2r[1][2], h3 = D1[3] + b2r[1][3];
                rs[1][0] += ev ? h0 : 0.f; rq[1][0] += ev ? h0*h0 : 0.f;
                rs[1][1] += ev ? h1 : 0.f; rq[1][1] += ev ? h1*h1 : 0.f;
                rs[1][2] += ev ? h2 : 0.f; rq[1][2] += ev ? h2*h2 : 0.f;
                rs[1][3] += ev ? h3 : 0.f; rq[1][3] += ev ? h3*h3 : 0.f;
                unsigned lo = (unsigned)f2bf(h0) | ((unsigned)f2bf(h1) << 16);
                unsigned hi = (unsigned)f2bf(h2) | ((unsigned)f2bf(h3) << 16);
                h2raw[((size_t)gblk * 8 + p * 2 + 1) * 64 + lane] = make_uint2(lo, hi);
            }
        }
    }

    // ---- stats reduction: in-wave over l15, then LDS across waves ----
    __syncthreads();
    if (t < 256) red[t] = 0.f;
    __syncthreads();
    #pragma unroll
    for (int ot = 0; ot < 2; ++ot) {
        #pragma unroll
        for (int r = 0; r < 4; ++r) {
            float a = rs[ot][r], b = rq[ot][r];
            #pragma unroll
            for (int m = 1; m <= 8; m <<= 1) {
                a += __shfl_xor(a, m, 64);
                b += __shfl_xor(b, m, 64);
            }
            if (l15 == 0) {
                int ch = p * 32 + ot * 16 + l4 * 4 + r;
                atomicAdd(&red[ch], a);
                atomicAdd(&red[128 + ch], b);
            }
        }
    }
    __syncthreads();
    if (t < 256) partials[(size_t)blockIdx.x * 256 + t] = red[t];
}

// ---------------------------------------------------------------------------
// Kernel S3: out[e] = b3 + sum_o W3[o]*relu(bn2(h2[e,o])), reading raw frags.
// ---------------------------------------------------------------------------
__global__ __launch_bounds__(256) void output_kernel(
    const uint2* __restrict__ h2raw,
    const float* __restrict__ scale2, const float* __restrict__ shift2,
    const float* __restrict__ W3, const float* __restrict__ b3,
    float* __restrict__ out, int E)
{
    __shared__ float sc_s[128], sh_s[128], w3_s[128];
    const int t = threadIdx.x;
    if (t < 128) { sc_s[t] = scale2[t]; sh_s[t] = shift2[t]; w3_s[t] = W3[t]; }
    __syncthreads();
    const int wv = t >> 6;
    const int lane = t & 63;
    const int l15 = lane & 15;
    const int l4 = lane >> 4;
    const float bias = b3[0];
    const int ngrp = (E + 15) >> 4;
    for (int g = blockIdx.x * 4 + wv; g < ngrp; g += gridDim.x * 4) {
        float acc = 0.f;
        #pragma unroll
        for (int w = 0; w < 8; ++w) {
            uint2 raw = h2raw[((size_t)g * 8 + w) * 64 + lane];
            const int o = w * 16 + l4 * 4;
            float4 sc = *(const float4*)(sc_s + o);
            float4 sh = *(const float4*)(sh_s + o);
            float4 w3 = *(const float4*)(w3_s + o);
            float h0 = bf2f_lo(raw.x), h1 = bf2f_hi(raw.x);
            float h2 = bf2f_lo(raw.y), h3 = bf2f_hi(raw.y);
            acc += fmaxf(h0 * sc.x + sh.x, 0.f) * w3.x;
            acc += fmaxf(h1 * sc.y + sh.y, 0.f) * w3.y;
            acc += fmaxf(h2 * sc.z + sh.z, 0.f) * w3.z;
            acc += fmaxf(h3 * sc.w + sh.w, 0.f) * w3.w;
        }
        acc += __shfl_xor(acc, 16, 64);
        acc += __shfl_xor(acc, 32, 64);
        const int e = g * 16 + l15;
        if (l4 == 0 && e < E) out[e] = acc + bias;
    }
}

// ---------------------------------------------------------------------------
extern "C" void kernel_launch(void* const* d_in, const int* in_sizes, int n_in,
                              void* d_out, int out_size, void* d_ws, size_t ws_size,
                              hipStream_t stream)
{
    const float* x   = (const float*)d_in[0];
    const int*   ei  = (const int*)d_in[1];
    const float* W1  = (const float*)d_in[2];
    const float* b1  = (const float*)d_in[3];
    const float* g1  = (const float*)d_in[4];
    const float* be1 = (const float*)d_in[5];
    const float* W2  = (const float*)d_in[6];
    const float* b2  = (const float*)d_in[7];
    const float* g2  = (const float*)d_in[8];
    const float* be2 = (const float*)d_in[9];
    const float* W3  = (const float*)d_in[10];
    const float* b3  = (const float*)d_in[11];

    const int N = in_sizes[0] / CH;
    const int E = out_size;
    const int* src = ei;
    const int* dst = ei + E;

    const int S1_BLOCKS = 512;
    const int S2_BLOCKS = 512;
    const size_t ngrp16 = (size_t)((E + 15) >> 4);

    // workspace layout (16B-aligned)
    unsigned short* u_bf = (unsigned short*)d_ws;             // N*128 bf16
    unsigned short* v_bf = u_bf + (size_t)N * CH;             // N*128 bf16
    uint2* h2raw = (uint2*)(v_bf + (size_t)N * CH);           // ngrp16*512 uint2
    float* part1 = (float*)(h2raw + ngrp16 * 512);            // S1_BLOCKS*256
    float* part2 = part1 + (size_t)S1_BLOCKS * 256;           // S2_BLOCKS*256
    float* scale1 = part2 + (size_t)S2_BLOCKS * 256;
    float* shift1 = scale1 + CH;
    float* scale2 = shift1 + CH;
    float* shift2 = scale2 + CH;
    float* out = (float*)d_out;

    node_linear_kernel<<<(N + 31) / 32, 256, 0, stream>>>(x, W1, u_bf, v_bf, N);
    stats1_kernel<<<S1_BLOCKS, 256, 0, stream>>>(u_bf, v_bf, src, dst, b1, part1, E);
    finalize_kernel<<<1, 256, 0, stream>>>(part1, S1_BLOCKS, g1, be1, scale1, shift1, 1.0f / (float)E);
    layer2_kernel<<<S2_BLOCKS, 512, 0, stream>>>(u_bf, v_bf, src, dst, b1, scale1, shift1,
                                                 W2, b2, h2raw, part2, E);
    finalize_kernel<<<1, 256, 0, stream>>>(part2, S2_BLOCKS, g2, be2, scale2, shift2, 1.0f / (float)E);
    output_kernel<<<2048, 256, 0, stream>>>(h2raw, scale2, shift2, W3, b3, out, E);
}

// Round 3
// 384.385 us; speedup vs baseline: 2.4327x; 1.1110x over previous
//
#include <hip/hip_runtime.h>
#include <hip/hip_bf16.h>

#define CH 128
#define CH4 32

constexpr float BN_EPS = 1e-5f;

typedef short bf16x8 __attribute__((ext_vector_type(8)));
typedef float f32x4  __attribute__((ext_vector_type(4)));

__device__ __forceinline__ unsigned f2bf(float f) {
    unsigned u = __float_as_uint(f);
    return (u + 0x7fffu + ((u >> 16) & 1u)) >> 16;   // RNE
}
__device__ __forceinline__ float bf2f_lo(unsigned u) { return __uint_as_float(u << 16); }
__device__ __forceinline__ float bf2f_hi(unsigned u) { return __uint_as_float(u & 0xffff0000u); }
__device__ __forceinline__ float dot4(float4 a, float4 b) {
    return a.x*b.x + a.y*b.y + a.z*b.z + a.w*b.w;
}

// ---------------------------------------------------------------------------
// Kernel U: u[n] = W1[:, :128] @ x[n],  v[n] = W1[:, 128:] @ x[n]  (bf16 out)
// ---------------------------------------------------------------------------
__global__ __launch_bounds__(256) void node_linear_kernel(
    const float* __restrict__ x, const float* __restrict__ W1,
    unsigned short* __restrict__ u_bf, unsigned short* __restrict__ v_bf, int N)
{
    __shared__ float4 xs[32 * 32];   // 32 nodes x 32 float4 (16 KB)
    const int t = threadIdx.x;
    const int n0 = blockIdx.x * 32;
    const float4* x4 = (const float4*)x;
    #pragma unroll
    for (int k = 0; k < 4; ++k) {
        int flat = t + k * 256;
        int row = flat >> 5, c4 = flat & 31;
        int n = n0 + row;
        xs[flat] = (n < N) ? x4[(size_t)n * CH4 + c4] : make_float4(0.f, 0.f, 0.f, 0.f);
    }
    __syncthreads();

    const int o = t & 127;
    const int half = t >> 7;
    const float4* W14 = (const float4*)W1;   // [128][64] float4
    float accu[16], accv[16];
    #pragma unroll
    for (int n = 0; n < 16; ++n) { accu[n] = 0.f; accv[n] = 0.f; }

    #pragma unroll 4
    for (int c4 = 0; c4 < 32; ++c4) {
        float4 wa = W14[o * 64 + c4];
        float4 wb = W14[o * 64 + 32 + c4];
        #pragma unroll
        for (int n = 0; n < 16; ++n) {
            float4 xv = xs[(half * 16 + n) * 32 + c4];
            accu[n] += dot4(wa, xv);
            accv[n] += dot4(wb, xv);
        }
    }
    #pragma unroll
    for (int n = 0; n < 16; ++n) {
        int node = n0 + half * 16 + n;
        if (node < N) {
            u_bf[(size_t)node * CH + o] = (unsigned short)f2bf(accu[n]);
            v_bf[(size_t)node * CH + o] = (unsigned short)f2bf(accv[n]);
        }
    }
}

// ---------------------------------------------------------------------------
// Kernel S1: per-edge h1 = u[src]+v[dst]+b1; sum/sumsq partials; optionally
// store h1 (bf16) so layer2 can stream instead of re-gathering.
// thread: c16 = t&15 owns 8 channels; eslot = t>>4 -> 16 edges/block-iter.
// ---------------------------------------------------------------------------
__global__ __launch_bounds__(256, 8) void stats1h1_kernel(
    const unsigned short* __restrict__ u_bf, const unsigned short* __restrict__ v_bf,
    const int* __restrict__ src, const int* __restrict__ dst,
    const float* __restrict__ b1, unsigned short* __restrict__ h1,
    float* __restrict__ partials, int E)
{
    const int t = threadIdx.x;
    const int c16 = t & 15;
    const int cb = c16 * 8;
    const int eslot = t >> 4;
    const float4 bva = *(const float4*)(b1 + cb);
    const float4 bvb = *(const float4*)(b1 + cb + 4);

    float rs[8] = {0.f,0.f,0.f,0.f,0.f,0.f,0.f,0.f};
    float rq[8] = {0.f,0.f,0.f,0.f,0.f,0.f,0.f,0.f};

    const int iters = (E + 15) >> 4;
    for (int it = blockIdx.x; it < iters; it += gridDim.x) {
        int e = it * 16 + eslot;
        if (e < E) {
            int s = src[e], d = dst[e];
            uint4 ua = *(const uint4*)(u_bf + (size_t)s * CH + cb);
            uint4 va = *(const uint4*)(v_bf + (size_t)d * CH + cb);
            float h[8];
            h[0] = bf2f_lo(ua.x) + bf2f_lo(va.x) + bva.x;
            h[1] = bf2f_hi(ua.x) + bf2f_hi(va.x) + bva.y;
            h[2] = bf2f_lo(ua.y) + bf2f_lo(va.y) + bva.z;
            h[3] = bf2f_hi(ua.y) + bf2f_hi(va.y) + bva.w;
            h[4] = bf2f_lo(ua.z) + bf2f_lo(va.z) + bvb.x;
            h[5] = bf2f_hi(ua.z) + bf2f_hi(va.z) + bvb.y;
            h[6] = bf2f_lo(ua.w) + bf2f_lo(va.w) + bvb.z;
            h[7] = bf2f_hi(ua.w) + bf2f_hi(va.w) + bvb.w;
            #pragma unroll
            for (int k = 0; k < 8; ++k) { rs[k] += h[k]; rq[k] += h[k] * h[k]; }
            if (h1) {
                uint4 pk;
                pk.x = f2bf(h[0]) | (f2bf(h[1]) << 16);
                pk.y = f2bf(h[2]) | (f2bf(h[3]) << 16);
                pk.z = f2bf(h[4]) | (f2bf(h[5]) << 16);
                pk.w = f2bf(h[6]) | (f2bf(h[7]) << 16);
                *(uint4*)(h1 + (size_t)e * CH + cb) = pk;
            }
        }
    }

    __shared__ float red[256];
    red[t] = 0.f;
    __syncthreads();
    #pragma unroll
    for (int k = 0; k < 8; ++k) {
        atomicAdd(&red[cb + k], rs[k]);
        atomicAdd(&red[128 + cb + k], rq[k]);
    }
    __syncthreads();
    partials[(size_t)blockIdx.x * 256 + t] = red[t];
}

// ---------------------------------------------------------------------------
// Finalize: mean/var -> scale/shift (1024 threads, 8 slices per channel)
// ---------------------------------------------------------------------------
__global__ __launch_bounds__(1024) void finalize_kernel(
    const float* __restrict__ partials, int nblocks,
    const float* __restrict__ gamma, const float* __restrict__ beta,
    float* __restrict__ scale, float* __restrict__ shift, float invE)
{
    __shared__ float accs[1024], accq[1024];
    const int t = threadIdx.x;
    const int ch = t & 127;
    const int sl = t >> 7;   // 0..7
    float s = 0.f, q = 0.f;
    for (int b = sl; b < nblocks; b += 8) {
        s += partials[(size_t)b * 256 + ch];
        q += partials[(size_t)b * 256 + 128 + ch];
    }
    accs[t] = s; accq[t] = q;
    __syncthreads();
    if (t < 128) {
        float st = 0.f, qt = 0.f;
        #pragma unroll
        for (int k = 0; k < 8; ++k) { st += accs[k * 128 + t]; qt += accq[k * 128 + t]; }
        float mean = st * invE;
        float var = fmaxf(qt * invE - mean * mean, 0.f);
        float sc = gamma[t] * rsqrtf(var + BN_EPS);
        scale[t] = sc;
        shift[t] = beta[t] - mean * sc;
    }
}

// ---------------------------------------------------------------------------
// Kernel S2 (MFMA): per 64-edge tile: y = relu(h1*sc1 + sh1) bf16 into
// swizzled LDS (h1 streamed if materialized, else re-gathered from u/v);
// D = W2frags x y via mfma 16x16x32; stats2; h2 stored raw fragment order.
// ---------------------------------------------------------------------------
__global__ __launch_bounds__(512, 4) void layer2_kernel(
    const unsigned short* __restrict__ u_bf, const unsigned short* __restrict__ v_bf,
    const int* __restrict__ src, const int* __restrict__ dst,
    const float* __restrict__ b1,
    const float* __restrict__ scale1, const float* __restrict__ shift1,
    const float* __restrict__ W2, const float* __restrict__ b2,
    const unsigned short* __restrict__ h1,
    uint2* __restrict__ h2raw, float* __restrict__ partials, int E)
{
    __shared__ short ybuf[64 * 128];   // 16 KB, XOR-swizzled bf16 y tile
    __shared__ float red[256];

    const int t = threadIdx.x;
    const int lane = t & 63;
    const int wv = t >> 6;      // wave 0..7
    const int p = wv & 3;       // o base = p*32
    const int h = wv >> 2;      // e-half
    const int l15 = lane & 15;
    const int l4  = lane >> 4;

    // --- stationary W2 A-fragments ---
    bf16x8 wfrag[2][4];
    #pragma unroll
    for (int ot = 0; ot < 2; ++ot) {
        int o = p * 32 + ot * 16 + l15;
        #pragma unroll
        for (int kk = 0; kk < 4; ++kk) {
            const float* wp = W2 + (size_t)o * CH + kk * 32 + l4 * 8;
            float4 a = *(const float4*)wp;
            float4 bq = *(const float4*)(wp + 4);
            bf16x8 f;
            f[0]=(short)f2bf(a.x);  f[1]=(short)f2bf(a.y);
            f[2]=(short)f2bf(a.z);  f[3]=(short)f2bf(a.w);
            f[4]=(short)f2bf(bq.x); f[5]=(short)f2bf(bq.y);
            f[6]=(short)f2bf(bq.z); f[7]=(short)f2bf(bq.w);
            wfrag[ot][kk] = f;
        }
    }
    float b2r[2][4];
    #pragma unroll
    for (int ot = 0; ot < 2; ++ot)
        #pragma unroll
        for (int r = 0; r < 4; ++r)
            b2r[ot][r] = b2[p * 32 + ot * 16 + l4 * 4 + r];

    // --- build-phase constants: thread owns channels cb..cb+7 ---
    const int c16 = t & 15;
    const int cb = c16 * 8;
    const int ebase = t >> 4;
    const float4 sca = *(const float4*)(scale1 + cb);
    const float4 scb = *(const float4*)(scale1 + cb + 4);
    const float4 sha = *(const float4*)(shift1 + cb);
    const float4 shb = *(const float4*)(shift1 + cb + 4);
    const float4 b1a = *(const float4*)(b1 + cb);
    const float4 b1b = *(const float4*)(b1 + cb + 4);

    float rs[2][4] = {{0.f,0.f,0.f,0.f},{0.f,0.f,0.f,0.f}};
    float rq[2][4] = {{0.f,0.f,0.f,0.f},{0.f,0.f,0.f,0.f}};

    const int ntiles = (E + 63) >> 6;
    for (int tile = blockIdx.x; tile < ntiles; tile += gridDim.x) {
        __syncthreads();   // previous tile's ybuf reads complete
        #pragma unroll
        for (int ee = 0; ee < 2; ++ee) {
            const int e_loc = ebase + ee * 32;
            const int e = tile * 64 + e_loc;
            bf16x8 y8 = {0,0,0,0,0,0,0,0};
            if (e < E) {
                float f[8];
                if (h1) {   // streamed h1 (b1 already folded in)
                    uint4 hr = *(const uint4*)(h1 + (size_t)e * CH + cb);
                    f[0] = bf2f_lo(hr.x); f[1] = bf2f_hi(hr.x);
                    f[2] = bf2f_lo(hr.y); f[3] = bf2f_hi(hr.y);
                    f[4] = bf2f_lo(hr.z); f[5] = bf2f_hi(hr.z);
                    f[6] = bf2f_lo(hr.w); f[7] = bf2f_hi(hr.w);
                } else {    // fallback: re-gather
                    int s = src[e], d = dst[e];
                    uint4 ua = *(const uint4*)(u_bf + (size_t)s * CH + cb);
                    uint4 va = *(const uint4*)(v_bf + (size_t)d * CH + cb);
                    f[0] = bf2f_lo(ua.x) + bf2f_lo(va.x) + b1a.x;
                    f[1] = bf2f_hi(ua.x) + bf2f_hi(va.x) + b1a.y;
                    f[2] = bf2f_lo(ua.y) + bf2f_lo(va.y) + b1a.z;
                    f[3] = bf2f_hi(ua.y) + bf2f_hi(va.y) + b1a.w;
                    f[4] = bf2f_lo(ua.z) + bf2f_lo(va.z) + b1b.x;
                    f[5] = bf2f_hi(ua.z) + bf2f_hi(va.z) + b1b.y;
                    f[6] = bf2f_lo(ua.w) + bf2f_lo(va.w) + b1b.z;
                    f[7] = bf2f_hi(ua.w) + bf2f_hi(va.w) + b1b.w;
                }
                y8[0] = (short)f2bf(fmaxf(f[0] * sca.x + sha.x, 0.f));
                y8[1] = (short)f2bf(fmaxf(f[1] * sca.y + sha.y, 0.f));
                y8[2] = (short)f2bf(fmaxf(f[2] * sca.z + sha.z, 0.f));
                y8[3] = (short)f2bf(fmaxf(f[3] * sca.w + sha.w, 0.f));
                y8[4] = (short)f2bf(fmaxf(f[4] * scb.x + shb.x, 0.f));
                y8[5] = (short)f2bf(fmaxf(f[5] * scb.y + shb.y, 0.f));
                y8[6] = (short)f2bf(fmaxf(f[6] * scb.z + shb.z, 0.f));
                y8[7] = (short)f2bf(fmaxf(f[7] * scb.w + shb.w, 0.f));
            }
            const int slot = c16 ^ (e_loc & 7);
            *(bf16x8*)(ybuf + e_loc * 128 + slot * 8) = y8;
        }
        __syncthreads();

        // ---- MFMA + epilogue ----
        #pragma unroll
        for (int g2 = 0; g2 < 2; ++g2) {
            const int g = h * 2 + g2;
            const int erow = g * 16 + l15;
            f32x4 D0 = {0.f, 0.f, 0.f, 0.f};
            f32x4 D1 = {0.f, 0.f, 0.f, 0.f};
            #pragma unroll
            for (int kk = 0; kk < 4; ++kk) {
                const int slot = (kk * 4 + l4) ^ (l15 & 7);
                bf16x8 yf = *(const bf16x8*)(ybuf + erow * 128 + slot * 8);
                D0 = __builtin_amdgcn_mfma_f32_16x16x32_bf16(wfrag[0][kk], yf, D0, 0, 0, 0);
                D1 = __builtin_amdgcn_mfma_f32_16x16x32_bf16(wfrag[1][kk], yf, D1, 0, 0, 0);
            }
            const int gblk = tile * 4 + g;
            const bool ev = ((size_t)gblk * 16 + l15) < (size_t)E;
            {   // ot = 0
                float h0 = D0[0] + b2r[0][0], h1v = D0[1] + b2r[0][1];
                float h2 = D0[2] + b2r[0][2], h3 = D0[3] + b2r[0][3];
                rs[0][0] += ev ? h0 : 0.f;  rq[0][0] += ev ? h0*h0 : 0.f;
                rs[0][1] += ev ? h1v : 0.f; rq[0][1] += ev ? h1v*h1v : 0.f;
                rs[0][2] += ev ? h2 : 0.f;  rq[0][2] += ev ? h2*h2 : 0.f;
                rs[0][3] += ev ? h3 : 0.f;  rq[0][3] += ev ? h3*h3 : 0.f;
                unsigned lo = f2bf(h0) | (f2bf(h1v) << 16);
                unsigned hi = f2bf(h2) | (f2bf(h3) << 16);
                h2raw[((size_t)gblk * 8 + p * 2 + 0) * 64 + lane] = make_uint2(lo, hi);
            }
            {   // ot = 1
                float h0 = D1[0] + b2r[1][0], h1v = D1[1] + b2r[1][1];
                float h2 = D1[2] + b2r[1][2], h3 = D1[3] + b2r[1][3];
                rs[1][0] += ev ? h0 : 0.f;  rq[1][0] += ev ? h0*h0 : 0.f;
                rs[1][1] += ev ? h1v : 0.f; rq[1][1] += ev ? h1v*h1v : 0.f;
                rs[1][2] += ev ? h2 : 0.f;  rq[1][2] += ev ? h2*h2 : 0.f;
                rs[1][3] += ev ? h3 : 0.f;  rq[1][3] += ev ? h3*h3 : 0.f;
                unsigned lo = f2bf(h0) | (f2bf(h1v) << 16);
                unsigned hi = f2bf(h2) | (f2bf(h3) << 16);
                h2raw[((size_t)gblk * 8 + p * 2 + 1) * 64 + lane] = make_uint2(lo, hi);
            }
        }
    }

    // ---- stats reduction ----
    __syncthreads();
    if (t < 256) red[t] = 0.f;
    __syncthreads();
    #pragma unroll
    for (int ot = 0; ot < 2; ++ot) {
        #pragma unroll
        for (int r = 0; r < 4; ++r) {
            float a = rs[ot][r], b = rq[ot][r];
            #pragma unroll
            for (int m = 1; m <= 8; m <<= 1) {
                a += __shfl_xor(a, m, 64);
                b += __shfl_xor(b, m, 64);
            }
            if (l15 == 0) {
                int ch = p * 32 + ot * 16 + l4 * 4 + r;
                atomicAdd(&red[ch], a);
                atomicAdd(&red[128 + ch], b);
            }
        }
    }
    __syncthreads();
    if (t < 256) partials[(size_t)blockIdx.x * 256 + t] = red[t];
}

// ---------------------------------------------------------------------------
// Kernel S3: out[e] = b3 + sum_o W3[o]*relu(bn2(h2[e,o])), raw fragment reads.
// ---------------------------------------------------------------------------
__global__ __launch_bounds__(256) void output_kernel(
    const uint2* __restrict__ h2raw,
    const float* __restrict__ scale2, const float* __restrict__ shift2,
    const float* __restrict__ W3, const float* __restrict__ b3,
    float* __restrict__ out, int E)
{
    __shared__ float sc_s[128], sh_s[128], w3_s[128];
    const int t = threadIdx.x;
    if (t < 128) { sc_s[t] = scale2[t]; sh_s[t] = shift2[t]; w3_s[t] = W3[t]; }
    __syncthreads();
    const int wv = t >> 6;
    const int lane = t & 63;
    const int l15 = lane & 15;
    const int l4 = lane >> 4;
    const float bias = b3[0];
    const int ngrp = (E + 15) >> 4;
    for (int g = blockIdx.x * 4 + wv; g < ngrp; g += gridDim.x * 4) {
        float acc = 0.f;
        #pragma unroll
        for (int w = 0; w < 8; ++w) {
            uint2 raw = h2raw[((size_t)g * 8 + w) * 64 + lane];
            const int o = w * 16 + l4 * 4;
            float4 sc = *(const float4*)(sc_s + o);
            float4 sh = *(const float4*)(sh_s + o);
            float4 w3 = *(const float4*)(w3_s + o);
            float h0 = bf2f_lo(raw.x), h1 = bf2f_hi(raw.x);
            float h2 = bf2f_lo(raw.y), h3 = bf2f_hi(raw.y);
            acc += fmaxf(h0 * sc.x + sh.x, 0.f) * w3.x;
            acc += fmaxf(h1 * sc.y + sh.y, 0.f) * w3.y;
            acc += fmaxf(h2 * sc.z + sh.z, 0.f) * w3.z;
            acc += fmaxf(h3 * sc.w + sh.w, 0.f) * w3.w;
        }
        acc += __shfl_xor(acc, 16, 64);
        acc += __shfl_xor(acc, 32, 64);
        const int e = g * 16 + l15;
        if (l4 == 0 && e < E) out[e] = acc + bias;
    }
}

// ---------------------------------------------------------------------------
extern "C" void kernel_launch(void* const* d_in, const int* in_sizes, int n_in,
                              void* d_out, int out_size, void* d_ws, size_t ws_size,
                              hipStream_t stream)
{
    const float* x   = (const float*)d_in[0];
    const int*   ei  = (const int*)d_in[1];
    const float* W1  = (const float*)d_in[2];
    const float* b1  = (const float*)d_in[3];
    const float* g1  = (const float*)d_in[4];
    const float* be1 = (const float*)d_in[5];
    const float* W2  = (const float*)d_in[6];
    const float* b2  = (const float*)d_in[7];
    const float* g2  = (const float*)d_in[8];
    const float* be2 = (const float*)d_in[9];
    const float* W3  = (const float*)d_in[10];
    const float* b3  = (const float*)d_in[11];

    const int N = in_sizes[0] / CH;
    const int E = out_size;
    const int* src = ei;
    const int* dst = ei + E;

    const int S1_BLOCKS = 2048;
    const int S2_BLOCKS = 1024;
    const size_t ngblk = (size_t)((E + 63) >> 6) * 4;   // 16-edge groups, tile-padded

    // workspace layout (16B-aligned)
    unsigned short* u_bf = (unsigned short*)d_ws;              // N*128 bf16
    unsigned short* v_bf = u_bf + (size_t)N * CH;              // N*128 bf16
    uint2* h2raw = (uint2*)(v_bf + (size_t)N * CH);            // ngblk*8*64 uint2
    float* part1 = (float*)(h2raw + ngblk * 8 * 64);           // S1_BLOCKS*256
    float* part2 = part1 + (size_t)S1_BLOCKS * 256;            // S2_BLOCKS*256
    float* scale1 = part2 + (size_t)S2_BLOCKS * 256;
    float* shift1 = scale1 + CH;
    float* scale2 = shift1 + CH;
    float* shift2 = scale2 + CH;
    unsigned short* h1 = (unsigned short*)(shift2 + CH + 4);   // E*128 bf16 (optional)
    float* out = (float*)d_out;

    const size_t base_bytes = (size_t)((char*)h1 - (char*)d_ws);
    const size_t h1_bytes = (size_t)E * CH * sizeof(unsigned short);
    const bool useH1 = (base_bytes + h1_bytes + 256) <= ws_size;
    unsigned short* h1p = useH1 ? h1 : nullptr;

    node_linear_kernel<<<(N + 31) / 32, 256, 0, stream>>>(x, W1, u_bf, v_bf, N);
    stats1h1_kernel<<<S1_BLOCKS, 256, 0, stream>>>(u_bf, v_bf, src, dst, b1, h1p, part1, E);
    finalize_kernel<<<1, 1024, 0, stream>>>(part1, S1_BLOCKS, g1, be1, scale1, shift1, 1.0f / (float)E);
    layer2_kernel<<<S2_BLOCKS, 512, 0, stream>>>(u_bf, v_bf, src, dst, b1, scale1, shift1,
                                                 W2, b2, h1p, h2raw, part2, E);
    finalize_kernel<<<1, 1024, 0, stream>>>(part2, S2_BLOCKS, g2, be2, scale2, shift2, 1.0f / (float)E);
    output_kernel<<<2048, 256, 0, stream>>>(h2raw, scale2, shift2, W3, b3, out, E);
}